// Round 3
// baseline (362.860 us; speedup 1.0000x reference)
//
#include <hip/hip_runtime.h>

// Problem constants (match reference)
#define BB 16
#define CC 256
#define RR 16
#define HWPLANE 16384              // 128*128 floats per (b,c) plane
#define NBLOCKS 512
#define NSTAGES 4                  // 4 batches per stage
#define PLANES_PER_STAGE 1024      // 4 batches * 256 channels
#define PPB 2                      // planes per block per stage

using f32x4 = __attribute__((ext_vector_type(4))) float;

// ---------------------------------------------------------------------------
// Tiny init kernel: zero the spin-barrier state each call (d_ws is poisoned
// 0xAA before timing and never re-poisoned; barrier must start from 0).
// ---------------------------------------------------------------------------
__global__ void init_kernel(unsigned* bar) {
    if (threadIdx.x < 2) bar[threadIdx.x] = 0u;
}

// Device-scope sense-counting barrier. All NBLOCKS must be co-resident:
// 512 blocks / 256 CUs = 2 blocks/CU of 4 waves -> resident at any VGPR/LDS.
__device__ __forceinline__ void grid_barrier(unsigned* cnt, unsigned* gen) {
    __syncthreads();
    if (threadIdx.x == 0) {
        unsigned g = __hip_atomic_load(gen, __ATOMIC_RELAXED,
                                       __HIP_MEMORY_SCOPE_AGENT);
        unsigned arrived = __hip_atomic_fetch_add(cnt, 1u, __ATOMIC_ACQ_REL,
                                                  __HIP_MEMORY_SCOPE_AGENT);
        if (arrived == NBLOCKS - 1) {
            __hip_atomic_store(cnt, 0u, __ATOMIC_RELAXED,
                               __HIP_MEMORY_SCOPE_AGENT);
            __hip_atomic_fetch_add(gen, 1u, __ATOMIC_RELEASE,
                                   __HIP_MEMORY_SCOPE_AGENT);
        } else {
            while (__hip_atomic_load(gen, __ATOMIC_ACQUIRE,
                                     __HIP_MEMORY_SCOPE_AGENT) == g) {
                __builtin_amdgcn_s_sleep(8);
            }
        }
    }
    __syncthreads();
}

// ---------------------------------------------------------------------------
// Persistent fused kernel. Per stage (4 batches = 64 MiB of x):
//   pool own 2 planes -> fused[bc] (agent store) -> grid barrier ->
//   redundant per-block SE for own batch -> scale own 2 planes (L2/L3-hot).
// Next stage's pool needs no barrier after scale (disjoint data).
// ---------------------------------------------------------------------------
__global__ __launch_bounds__(256, 4) void spse_fused_kernel(
    const float* __restrict__ x,
    const float* __restrict__ Wf,   // (C, 21)
    const float* __restrict__ bf,   // (C,)
    const float* __restrict__ W1,   // (C, r)
    const float* __restrict__ b1,   // (r,)
    const float* __restrict__ W2,   // (r, C)
    const float* __restrict__ b2,   // (C,)
    float* __restrict__ out,
    unsigned* __restrict__ bar,     // [0]=cnt [1]=gen
    float* __restrict__ fused)      // (B*C,)
{
    const int t    = threadIdx.x;
    const int lane = t & 63;
    const int wave = t >> 6;
    const int bx   = (t & 31) >> 3;
    const int blk  = blockIdx.x;

    __shared__ float wred[4][16];
    __shared__ float pb[PPB][16];     // 4x4 block maxes per owned plane
    __shared__ float hpart[16][16];   // [chunk][j] partials for h
    __shared__ float hl[RR];
    __shared__ float sv[PPB];

    for (int stage = 0; stage < NSTAGES; ++stage) {
        const int bc0 = stage * PLANES_PER_STAGE + blk * PPB;

        // ---- pool own planes ----
        for (int q = 0; q < PPB; ++q) {
            const f32x4* xp = (const f32x4*)(x + (size_t)(bc0 + q) * HWPLANE);
#pragma unroll
            for (int by = 0; by < 4; ++by) {
                float m = -3.402823466e+38f;
#pragma unroll
                for (int ii = 0; ii < 4; ++ii) {
                    f32x4 v = xp[(by * 4 + ii) * 256 + t];
                    m = fmaxf(m, fmaxf(fmaxf(v.x, v.y), fmaxf(v.z, v.w)));
                }
                m = fmaxf(m, __shfl_xor(m, 1));
                m = fmaxf(m, __shfl_xor(m, 2));
                m = fmaxf(m, __shfl_xor(m, 4));
                m = fmaxf(m, __shfl_xor(m, 32));
                if ((lane & 7) == 0 && lane < 32) wred[wave][by * 4 + bx] = m;
            }
            __syncthreads();
            if (t < 16)
                pb[q][t] = fmaxf(fmaxf(wred[0][t], wred[1][t]),
                                 fmaxf(wred[2][t], wred[3][t]));
            __syncthreads();
        }

        // ---- fused 21->1 linear for own planes (threads 0..PPB-1) ----
        if (t < PPB) {
            const int bc = bc0 + t;
            const int c  = bc & (CC - 1);
            const float* p = pb[t];
            float q0 = fmaxf(fmaxf(p[0],  p[1]),  fmaxf(p[4],  p[5]));
            float q1 = fmaxf(fmaxf(p[2],  p[3]),  fmaxf(p[6],  p[7]));
            float q2 = fmaxf(fmaxf(p[8],  p[9]),  fmaxf(p[12], p[13]));
            float q3 = fmaxf(fmaxf(p[10], p[11]), fmaxf(p[14], p[15]));
            float gm = fmaxf(fmaxf(q0, q1), fmaxf(q2, q3));
            const float* w = Wf + c * 21;
            float acc = bf[c] + gm * w[0]
                      + q0 * w[1] + q1 * w[2] + q2 * w[3] + q3 * w[4];
#pragma unroll
            for (int k = 0; k < 16; ++k) acc += p[k] * w[5 + k];
            __hip_atomic_store(&fused[bc], acc, __ATOMIC_RELAXED,
                               __HIP_MEMORY_SCOPE_AGENT);
        }

        // ---- wait for all pools of this stage ----
        grid_barrier(&bar[0], &bar[1]);

        // ---- redundant per-block SE for own batch ----
        const int b = bc0 >> 8;
        {
            const int j = t & 15, ch = t >> 4;
            float p = 0.f;
#pragma unroll
            for (int m = 0; m < 16; ++m) {
                const int cc = ch * 16 + m;
                float fv = __hip_atomic_load(&fused[b * CC + cc],
                                             __ATOMIC_RELAXED,
                                             __HIP_MEMORY_SCOPE_AGENT);
                p += fv * W1[cc * RR + j];
            }
            hpart[ch][j] = p;
        }
        __syncthreads();
        if (t < RR) {
            float a = b1[t];
#pragma unroll
            for (int ch = 0; ch < 16; ++ch) a += hpart[ch][t];
            hl[t] = fmaxf(a, 0.f);
        }
        __syncthreads();
        if (t < PPB) {
            const int c = (bc0 + t) & (CC - 1);
            float a = b2[c];
#pragma unroll
            for (int j = 0; j < RR; ++j) a += hl[j] * W2[j * CC + c];
            sv[t] = a;
        }
        __syncthreads();

        // ---- scale own planes (x re-read is L2/L3-hot; nt stores) ----
        for (int q = 0; q < PPB; ++q) {
            const float sc = sv[q];
            const f32x4* xp = (const f32x4*)(x + (size_t)(bc0 + q) * HWPLANE);
            f32x4* op = (f32x4*)(out + (size_t)(bc0 + q) * HWPLANE);
#pragma unroll
            for (int i = 0; i < 16; ++i) {
                f32x4 v = xp[i * 256 + t];
                __builtin_nontemporal_store(v * sc, &op[i * 256 + t]);
            }
        }
        __syncthreads();   // protect sv/pb before next stage overwrites
    }
}

extern "C" void kernel_launch(void* const* d_in, const int* in_sizes, int n_in,
                              void* d_out, int out_size, void* d_ws, size_t ws_size,
                              hipStream_t stream) {
    const float* x  = (const float*)d_in[0];
    const float* Wf = (const float*)d_in[1];
    const float* bf = (const float*)d_in[2];
    const float* W1 = (const float*)d_in[3];
    const float* b1 = (const float*)d_in[4];
    const float* W2 = (const float*)d_in[5];
    const float* b2 = (const float*)d_in[6];
    float* out = (float*)d_out;

    unsigned* bar  = (unsigned*)d_ws;
    float* fused   = (float*)((char*)d_ws + 256);   // B*C floats

    init_kernel<<<1, 64, 0, stream>>>(bar);
    spse_fused_kernel<<<NBLOCKS, 256, 0, stream>>>(
        x, Wf, bf, W1, b1, W2, b2, out, bar, fused);
}

// Round 4
// 264.866 us; speedup vs baseline: 1.3700x; 1.3700x over previous
//
#include <hip/hip_runtime.h>

// Problem constants
#define BB 16
#define CC 256
#define RR 16
#define HWPLANE 16384              // 128*128 floats per (b,c) plane
#define NBLOCKS 512
#define NSTAGES 4                  // 4 batches per stage
#define PLANES_PER_STAGE 1024      // 4 batches * 256 channels
#define PPB 2                      // planes per block per stage
#define BLOCKS_PER_BATCH 128       // 256 planes / PPB

using f32x4 = __attribute__((ext_vector_type(4))) float;

// ---------------------------------------------------------------------------
// Init: zero the 16 per-(stage,batch) barrier counters (ws is 0xAA-poisoned
// once and never re-poisoned; graph replays re-run this each call).
// ---------------------------------------------------------------------------
__global__ void init_kernel(unsigned* bar) {
    if (threadIdx.x < 16) bar[threadIdx.x] = 0u;
}

// Per-batch barrier: monotonic counter, RELAXED polls (no per-poll cache
// invalidate -- R3's mistake), one RELEASE fence before increment and one
// ACQUIRE fence after exit.
__device__ __forceinline__ void batch_barrier(unsigned* cnt) {
    __syncthreads();
    if (threadIdx.x == 0) {
        __builtin_amdgcn_fence(__ATOMIC_RELEASE, "agent");
        __hip_atomic_fetch_add(cnt, 1u, __ATOMIC_RELAXED,
                               __HIP_MEMORY_SCOPE_AGENT);
        unsigned v;
        do {
            __builtin_amdgcn_s_sleep(16);
            v = __hip_atomic_load(cnt, __ATOMIC_RELAXED,
                                  __HIP_MEMORY_SCOPE_AGENT);
        } while (v < BLOCKS_PER_BATCH);
        __builtin_amdgcn_fence(__ATOMIC_ACQUIRE, "agent");
    }
    __syncthreads();
}

// ---------------------------------------------------------------------------
// Persistent fused kernel. Per stage (4 batches = 64 MiB of x):
//   pool own 2 planes -> fused[bc] (agent, L2-bypass) -> per-batch barrier ->
//   redundant per-block SE for own batch -> scale own 2 planes (L2/L3-hot,
//   nontemporal out stores).
// ---------------------------------------------------------------------------
__global__ __launch_bounds__(256, 2) void spse_fused_kernel(
    const float* __restrict__ x,
    const float* __restrict__ Wf,   // (C, 21)
    const float* __restrict__ bf,   // (C,)
    const float* __restrict__ W1,   // (C, r)
    const float* __restrict__ b1,   // (r,)
    const float* __restrict__ W2,   // (r, C)
    const float* __restrict__ b2,   // (C,)
    float* __restrict__ out,
    unsigned* __restrict__ bar,     // 16 counters: [stage*4 + batchInStage]
    float* __restrict__ fused)      // (B*C,)
{
    const int t    = threadIdx.x;
    const int lane = t & 63;
    const int wave = t >> 6;
    const int bx   = (t & 31) >> 3;
    const int blk  = blockIdx.x;

    __shared__ float wred[4][16];
    __shared__ float pb[PPB][16];     // 4x4 block maxes per owned plane
    __shared__ float hpart[16][16];   // [chunk][j] partials for h
    __shared__ float hl[RR];
    __shared__ float sv[PPB];

    for (int stage = 0; stage < NSTAGES; ++stage) {
        const int bc0 = stage * PLANES_PER_STAGE + blk * PPB;

        // ---- pool own planes ----
        for (int q = 0; q < PPB; ++q) {
            const f32x4* xp = (const f32x4*)(x + (size_t)(bc0 + q) * HWPLANE);
#pragma unroll
            for (int by = 0; by < 4; ++by) {
                float m = -3.402823466e+38f;
#pragma unroll
                for (int ii = 0; ii < 4; ++ii) {
                    f32x4 v = xp[(by * 4 + ii) * 256 + t];
                    m = fmaxf(m, fmaxf(fmaxf(v.x, v.y), fmaxf(v.z, v.w)));
                }
                m = fmaxf(m, __shfl_xor(m, 1));
                m = fmaxf(m, __shfl_xor(m, 2));
                m = fmaxf(m, __shfl_xor(m, 4));
                m = fmaxf(m, __shfl_xor(m, 32));
                if ((lane & 7) == 0 && lane < 32) wred[wave][by * 4 + bx] = m;
            }
            __syncthreads();
            if (t < 16)
                pb[q][t] = fmaxf(fmaxf(wred[0][t], wred[1][t]),
                                 fmaxf(wred[2][t], wred[3][t]));
            __syncthreads();
        }

        // ---- fused 21->1 linear for own planes ----
        if (t < PPB) {
            const int bc = bc0 + t;
            const int c  = bc & (CC - 1);
            const float* p = pb[t];
            float q0 = fmaxf(fmaxf(p[0],  p[1]),  fmaxf(p[4],  p[5]));
            float q1 = fmaxf(fmaxf(p[2],  p[3]),  fmaxf(p[6],  p[7]));
            float q2 = fmaxf(fmaxf(p[8],  p[9]),  fmaxf(p[12], p[13]));
            float q3 = fmaxf(fmaxf(p[10], p[11]), fmaxf(p[14], p[15]));
            float gm = fmaxf(fmaxf(q0, q1), fmaxf(q2, q3));
            const float* w = Wf + c * 21;
            float acc = bf[c] + gm * w[0]
                      + q0 * w[1] + q1 * w[2] + q2 * w[3] + q3 * w[4];
#pragma unroll
            for (int k = 0; k < 16; ++k) acc += p[k] * w[5 + k];
            __hip_atomic_store(&fused[bc], acc, __ATOMIC_RELAXED,
                               __HIP_MEMORY_SCOPE_AGENT);
        }

        // ---- wait only for the 128 blocks of OUR batch ----
        batch_barrier(&bar[stage * 4 + (blk >> 7)]);

        // ---- redundant per-block SE for own batch ----
        const int b = bc0 >> 8;
        {
            const int j = t & 15, ch = t >> 4;
            float p = 0.f;
#pragma unroll
            for (int m = 0; m < 16; ++m) {
                const int cc = ch * 16 + m;
                float fv = __hip_atomic_load(&fused[b * CC + cc],
                                             __ATOMIC_RELAXED,
                                             __HIP_MEMORY_SCOPE_AGENT);
                p += fv * W1[cc * RR + j];
            }
            hpart[ch][j] = p;
        }
        __syncthreads();
        if (t < RR) {
            float a = b1[t];
#pragma unroll
            for (int ch = 0; ch < 16; ++ch) a += hpart[ch][t];
            hl[t] = fmaxf(a, 0.f);
        }
        __syncthreads();
        if (t < PPB) {
            const int c = (bc0 + t) & (CC - 1);
            float a = b2[c];
#pragma unroll
            for (int j = 0; j < RR; ++j) a += hl[j] * W2[j * CC + c];
            sv[t] = a;
        }
        __syncthreads();

        // ---- scale own planes (x re-read L2/L3-hot; nt stores) ----
        for (int q = 0; q < PPB; ++q) {
            const float sc = sv[q];
            const f32x4* xp = (const f32x4*)(x + (size_t)(bc0 + q) * HWPLANE);
            f32x4* op = (f32x4*)(out + (size_t)(bc0 + q) * HWPLANE);
#pragma unroll
            for (int i = 0; i < 16; ++i) {
                f32x4 v = xp[i * 256 + t];
                __builtin_nontemporal_store(v * sc, &op[i * 256 + t]);
            }
        }
        __syncthreads();   // protect pb/sv before next stage overwrites
    }
}

extern "C" void kernel_launch(void* const* d_in, const int* in_sizes, int n_in,
                              void* d_out, int out_size, void* d_ws, size_t ws_size,
                              hipStream_t stream) {
    const float* x  = (const float*)d_in[0];
    const float* Wf = (const float*)d_in[1];
    const float* bf = (const float*)d_in[2];
    const float* W1 = (const float*)d_in[3];
    const float* b1 = (const float*)d_in[4];
    const float* W2 = (const float*)d_in[5];
    const float* b2 = (const float*)d_in[6];
    float* out = (float*)d_out;

    unsigned* bar = (unsigned*)d_ws;
    float* fused  = (float*)((char*)d_ws + 256);   // B*C floats

    init_kernel<<<1, 64, 0, stream>>>(bar);
    spse_fused_kernel<<<NBLOCKS, 256, 0, stream>>>(
        x, Wf, bf, W1, b1, W2, b2, out, bar, fused);
}

// Round 7
// 137.621 us; speedup vs baseline: 2.6367x; 1.9246x over previous
//
#include <hip/hip_runtime.h>

// Problem constants
#define BB 16
#define CC 256
#define RR 16
#define HWPLANE 16384              // 128*128 floats per (b,c) plane
#define NGROUPS 4                  // 4 batches per group
#define PLANES_PER_GROUP 1024      // 4 * 256

using f32x4 = __attribute__((ext_vector_type(4))) float;

// ---------------------------------------------------------------------------
// Pool kernel (per group): one block per (b,c) plane. Hierarchical max pool
// (16 block-maxes of 32x32 tiles; rate-2/rate-1 derive from them) + fused
// 21->1 per-channel linear -> fused[bc]. Caching loads on purpose: they
// stage x in L2/L3 for the scale kernel launched right after (64 MiB/group
// reuse distance << 256 MiB Infinity Cache).
// ---------------------------------------------------------------------------
__global__ __launch_bounds__(256) void pool_fuse_kernel(
    const float* __restrict__ x,
    const float* __restrict__ Wf,   // (C, 21)
    const float* __restrict__ bf,   // (C,)
    float* __restrict__ fused,      // (B*C,)
    int plane0)
{
    const int bc = plane0 + blockIdx.x;
    const int c  = bc & (CC - 1);
    const f32x4* xp = (const f32x4*)(x + (size_t)bc * HWPLANE);

    const int t    = threadIdx.x;
    const int lane = t & 63;
    const int wave = t >> 6;
    const int bx   = (t & 31) >> 3;

    __shared__ float wred[4][16];
    __shared__ float pb[16];

#pragma unroll
    for (int by = 0; by < 4; ++by) {
        float m = -3.402823466e+38f;
#pragma unroll
        for (int ii = 0; ii < 4; ++ii) {
            f32x4 v = xp[(by * 4 + ii) * 256 + t];
            m = fmaxf(m, fmaxf(fmaxf(v.x, v.y), fmaxf(v.z, v.w)));
        }
        m = fmaxf(m, __shfl_xor(m, 1));
        m = fmaxf(m, __shfl_xor(m, 2));
        m = fmaxf(m, __shfl_xor(m, 4));
        m = fmaxf(m, __shfl_xor(m, 32));
        if ((lane & 7) == 0 && lane < 32) wred[wave][by * 4 + bx] = m;
    }
    __syncthreads();

    if (t < 16)
        pb[t] = fmaxf(fmaxf(wred[0][t], wred[1][t]),
                      fmaxf(wred[2][t], wred[3][t]));
    __syncthreads();

    if (t == 0) {
        float q0 = fmaxf(fmaxf(pb[0],  pb[1]),  fmaxf(pb[4],  pb[5]));
        float q1 = fmaxf(fmaxf(pb[2],  pb[3]),  fmaxf(pb[6],  pb[7]));
        float q2 = fmaxf(fmaxf(pb[8],  pb[9]),  fmaxf(pb[12], pb[13]));
        float q3 = fmaxf(fmaxf(pb[10], pb[11]), fmaxf(pb[14], pb[15]));
        float g  = fmaxf(fmaxf(q0, q1), fmaxf(q2, q3));

        const float* w = Wf + c * 21;
        float acc = bf[c] + g * w[0]
                  + q0 * w[1] + q1 * w[2] + q2 * w[3] + q3 * w[4];
#pragma unroll
        for (int k = 0; k < 16; ++k) acc += pb[k] * w[5 + k];
        fused[bc] = acc;
    }
}

// ---------------------------------------------------------------------------
// Scale kernel (per group): one block per plane. Redundant per-block SE
// (h = relu(fused[b,:]@W1+b1), s = h.W2[:,c]+b2[c] -- ~4K MACs, free),
// then out = x * s with nontemporal stores (write stream must not evict
// the L3-staged x of the NEXT group). x re-read is L2/L3-hot.
// Same blockIdx->plane mapping as pool_fuse_kernel for XCD L2 alignment.
// ---------------------------------------------------------------------------
__global__ __launch_bounds__(256) void scale_se_kernel(
    const float* __restrict__ x,
    const float* __restrict__ W1,   // (C, r)
    const float* __restrict__ b1,   // (r,)
    const float* __restrict__ W2,   // (r, C)
    const float* __restrict__ b2,   // (C,)
    const float* __restrict__ fused,// (B*C,)
    float* __restrict__ out,
    int plane0)
{
    const int bc = plane0 + blockIdx.x;
    const int b  = bc >> 8;
    const int c  = bc & (CC - 1);
    const int t  = threadIdx.x;

    __shared__ float hpart[16][16];   // [chunk][j]
    __shared__ float hl[RR];
    __shared__ float svs;

    {   // h partials: thread (ch, j) accumulates 16 channels
        const int j = t & 15, ch = t >> 4;
        float p = 0.f;
#pragma unroll
        for (int m = 0; m < 16; ++m) {
            const int cc = ch * 16 + m;
            p += fused[b * CC + cc] * W1[cc * RR + j];
        }
        hpart[ch][j] = p;
    }
    __syncthreads();
    if (t < RR) {
        float a = b1[t];
#pragma unroll
        for (int ch = 0; ch < 16; ++ch) a += hpart[ch][t];
        hl[t] = fmaxf(a, 0.f);
    }
    __syncthreads();
    if (t == 0) {
        float a = b2[c];
#pragma unroll
        for (int j = 0; j < RR; ++j) a += hl[j] * W2[j * CC + c];
        svs = a;
    }
    __syncthreads();

    const float sc = svs;
    const f32x4* xp = (const f32x4*)(x + (size_t)bc * HWPLANE);
    f32x4* op = (f32x4*)(out + (size_t)bc * HWPLANE);
#pragma unroll
    for (int i = 0; i < 16; ++i) {
        f32x4 v = xp[i * 256 + t];
        __builtin_nontemporal_store(v * sc, &op[i * 256 + t]);
    }
}

extern "C" void kernel_launch(void* const* d_in, const int* in_sizes, int n_in,
                              void* d_out, int out_size, void* d_ws, size_t ws_size,
                              hipStream_t stream) {
    const float* x  = (const float*)d_in[0];
    const float* Wf = (const float*)d_in[1];
    const float* bf = (const float*)d_in[2];
    const float* W1 = (const float*)d_in[3];
    const float* b1 = (const float*)d_in[4];
    const float* W2 = (const float*)d_in[5];
    const float* b2 = (const float*)d_in[6];
    float* out = (float*)d_out;

    float* fused = (float*)d_ws;          // B*C floats

    for (int g = 0; g < NGROUPS; ++g) {
        const int plane0 = g * PLANES_PER_GROUP;
        pool_fuse_kernel<<<PLANES_PER_GROUP, 256, 0, stream>>>(
            x, Wf, bf, fused, plane0);
        scale_se_kernel<<<PLANES_PER_GROUP, 256, 0, stream>>>(
            x, W1, b1, W2, b2, fused, out, plane0);
    }
}

// Round 8
// 135.613 us; speedup vs baseline: 2.6757x; 1.0148x over previous
//
#include <hip/hip_runtime.h>

// Problem constants
#define BB 16
#define CC 256
#define RR 16
#define HWPLANE 16384              // 128*128 floats per (b,c) plane
#define NGROUPS 4                  // 4 batches per group
#define PLANES_PER_GROUP 1024      // 4 * 256

using f32x4 = __attribute__((ext_vector_type(4))) float;

// ---------------------------------------------------------------------------
// Combined stage kernel. Per block (1024 blocks):
//   A) if scale_plane0 >= 0: redundant SE for batch of plane (scale_plane0 +
//      blockIdx.x) using fused[] written by the PREVIOUS dispatch, then
//      out = x * s with nontemporal stores. x re-read is L3-hot (the
//      previous dispatch's pool phase streamed this 64 MiB group through L3).
//   B) if pool_plane0 >= 0: hierarchical max pool of plane (pool_plane0 +
//      blockIdx.x) -> fused[bc] for the NEXT dispatch. Cold HBM reads;
//      they overlap with phase A's NT write stream across blocks.
// Chain: pool0 | s0+p1 | s1+p2 | s2+p3 | s3  (5 dispatches, stream-ordered).
// ---------------------------------------------------------------------------
__global__ __launch_bounds__(256) void spse_stage_kernel(
    const float* __restrict__ x,
    const float* __restrict__ Wf,   // (C, 21)
    const float* __restrict__ bf,   // (C,)
    const float* __restrict__ W1,   // (C, r)
    const float* __restrict__ b1,   // (r,)
    const float* __restrict__ W2,   // (r, C)
    const float* __restrict__ b2,   // (C,)
    float* __restrict__ fused,      // (B*C,)
    float* __restrict__ out,
    int scale_plane0,               // -1 = no scale phase
    int pool_plane0)                // -1 = no pool phase
{
    const int t    = threadIdx.x;
    const int lane = t & 63;
    const int wave = t >> 6;
    const int bx   = (t & 31) >> 3;

    __shared__ float hpart[16][16];
    __shared__ float hl[RR];
    __shared__ float svs;
    __shared__ float wred[4][16];
    __shared__ float pb[16];

    // ---------------- Phase A: SE + scale (group g) ----------------
    if (scale_plane0 >= 0) {
        const int bc = scale_plane0 + blockIdx.x;
        const int b  = bc >> 8;
        const int c  = bc & (CC - 1);

        {   // h partials: thread (ch, j) accumulates 16 channels
            const int j = t & 15, ch = t >> 4;
            float p = 0.f;
#pragma unroll
            for (int m = 0; m < 16; ++m) {
                const int cc = ch * 16 + m;
                p += fused[b * CC + cc] * W1[cc * RR + j];
            }
            hpart[ch][j] = p;
        }
        __syncthreads();
        if (t < RR) {
            float a = b1[t];
#pragma unroll
            for (int ch = 0; ch < 16; ++ch) a += hpart[ch][t];
            hl[t] = fmaxf(a, 0.f);
        }
        __syncthreads();
        if (t == 0) {
            float a = b2[c];
#pragma unroll
            for (int j = 0; j < RR; ++j) a += hl[j] * W2[j * CC + c];
            svs = a;
        }
        __syncthreads();

        const float sc = svs;
        const f32x4* xp = (const f32x4*)(x + (size_t)bc * HWPLANE);
        f32x4* op = (f32x4*)(out + (size_t)bc * HWPLANE);
#pragma unroll
        for (int i = 0; i < 16; ++i) {
            f32x4 v = xp[i * 256 + t];
            __builtin_nontemporal_store(v * sc, &op[i * 256 + t]);
        }
    }

    // ---------------- Phase B: pool + fused linear (group g+1) ----------------
    if (pool_plane0 >= 0) {
        const int bc = pool_plane0 + blockIdx.x;
        const int c  = bc & (CC - 1);
        const f32x4* xp = (const f32x4*)(x + (size_t)bc * HWPLANE);

#pragma unroll
        for (int by = 0; by < 4; ++by) {
            float m = -3.402823466e+38f;
#pragma unroll
            for (int ii = 0; ii < 4; ++ii) {
                f32x4 v = xp[(by * 4 + ii) * 256 + t];
                m = fmaxf(m, fmaxf(fmaxf(v.x, v.y), fmaxf(v.z, v.w)));
            }
            m = fmaxf(m, __shfl_xor(m, 1));
            m = fmaxf(m, __shfl_xor(m, 2));
            m = fmaxf(m, __shfl_xor(m, 4));
            m = fmaxf(m, __shfl_xor(m, 32));
            if ((lane & 7) == 0 && lane < 32) wred[wave][by * 4 + bx] = m;
        }
        __syncthreads();

        if (t < 16)
            pb[t] = fmaxf(fmaxf(wred[0][t], wred[1][t]),
                          fmaxf(wred[2][t], wred[3][t]));
        __syncthreads();

        if (t == 0) {
            float q0 = fmaxf(fmaxf(pb[0],  pb[1]),  fmaxf(pb[4],  pb[5]));
            float q1 = fmaxf(fmaxf(pb[2],  pb[3]),  fmaxf(pb[6],  pb[7]));
            float q2 = fmaxf(fmaxf(pb[8],  pb[9]),  fmaxf(pb[12], pb[13]));
            float q3 = fmaxf(fmaxf(pb[10], pb[11]), fmaxf(pb[14], pb[15]));
            float g  = fmaxf(fmaxf(q0, q1), fmaxf(q2, q3));

            const float* w = Wf + c * 21;
            float acc = bf[c] + g * w[0]
                      + q0 * w[1] + q1 * w[2] + q2 * w[3] + q3 * w[4];
#pragma unroll
            for (int k = 0; k < 16; ++k) acc += pb[k] * w[5 + k];
            fused[bc] = acc;
        }
    }
}

extern "C" void kernel_launch(void* const* d_in, const int* in_sizes, int n_in,
                              void* d_out, int out_size, void* d_ws, size_t ws_size,
                              hipStream_t stream) {
    const float* x  = (const float*)d_in[0];
    const float* Wf = (const float*)d_in[1];
    const float* bf = (const float*)d_in[2];
    const float* W1 = (const float*)d_in[3];
    const float* b1 = (const float*)d_in[4];
    const float* W2 = (const float*)d_in[5];
    const float* b2 = (const float*)d_in[6];
    float* out = (float*)d_out;

    float* fused = (float*)d_ws;          // B*C floats

    // pool0
    spse_stage_kernel<<<PLANES_PER_GROUP, 256, 0, stream>>>(
        x, Wf, bf, W1, b1, W2, b2, fused, out, -1, 0);
    // scale(g) + pool(g+1)
    for (int g = 0; g < NGROUPS - 1; ++g) {
        spse_stage_kernel<<<PLANES_PER_GROUP, 256, 0, stream>>>(
            x, Wf, bf, W1, b1, W2, b2, fused, out,
            g * PLANES_PER_GROUP, (g + 1) * PLANES_PER_GROUP);
    }
    // scale3
    spse_stage_kernel<<<PLANES_PER_GROUP, 256, 0, stream>>>(
        x, Wf, bf, W1, b1, W2, b2, fused, out,
        (NGROUPS - 1) * PLANES_PER_GROUP, -1);
}